// Round 12
// baseline (777.524 us; speedup 1.0000x reference)
//
#include <hip/hip_runtime.h>

typedef __attribute__((ext_vector_type(8))) short bf16x8;
typedef __attribute__((ext_vector_type(4))) float f32x4;
typedef __attribute__((ext_vector_type(2))) unsigned int u32x2;
typedef __attribute__((ext_vector_type(4))) unsigned int u32x4;

#define LOG2E  1.442695040888963f
#define LOG2E2 2.885390081777927f

__device__ __forceinline__ unsigned cvt_pk_bf16(float lo, float hi){
  unsigned r; asm("v_cvt_pk_bf16_f32 %0, %1, %2" : "=v"(r) : "v"(lo), "v"(hi)); return r;
}

// ---------------- prologue 1: embproj[dir][tok][m] = (emb[tok]@Wx + b) * gate_scale ------
__global__ void embproj_kernel(const float* __restrict__ emb,
                               const float* __restrict__ Wx_f, const float* __restrict__ b_f,
                               const float* __restrict__ Wx_b, const float* __restrict__ b_b,
                               float* __restrict__ embproj){
  const int blk = blockIdx.x;
  const int dir = blk >> 9;
  const int tok = (blk >> 2) & 127;
  const int m   = (blk & 3)*256 + threadIdx.x;
  const float* Wx = dir ? Wx_b : Wx_f;
  const float* bb = dir ? b_b  : b_f;
  __shared__ float es[128];
  if (threadIdx.x < 128) es[threadIdx.x] = emb[tok*128 + threadIdx.x];
  __syncthreads();
  float acc = bb[m];
  #pragma unroll 4
  for (int e = 0; e < 128; e++) acc = fmaf(es[e], Wx[e*1024 + m], acc);
  const float s = ((m >> 8) == 2) ? LOG2E2 : LOG2E;
  embproj[(dir*128 + tok)*1024 + m] = acc * s;
}

// ---------------- prologue 2: pack Wh^T into MFMA A-frag order (bf16), pre-scaled ---------
// frag layout: [dir][mf(64)][kb(8)][lane(64)] x 16B; m = mf*16+(l&15),
// k-slot j: k = kb*32 + (l>>4)*4 + (j&3) + 16*(j>>2)   (A and B share the map)
__global__ void whpack_kernel(const float* __restrict__ Wh_f, const float* __restrict__ Wh_b,
                              u32x4* __restrict__ whpack){
  const int t = blockIdx.x*256 + threadIdx.x;
  const int lane = t & 63;
  const int kb   = (t >> 6) & 7;
  const int mf   = (t >> 9) & 63;
  const int dir  = t >> 15;
  const float* Wh = dir ? Wh_b : Wh_f;
  const int m = mf*16 + (lane & 15);
  const int kbase = kb*32 + ((lane >> 4) << 2);
  const float s = ((mf >> 4) == 2) ? LOG2E2 : LOG2E;
  u32x4 o;
  #pragma unroll
  for (int p = 0; p < 4; p++){
    const int k0 = kbase + (p & 1)*2 + (p >> 1)*16;
    unsigned pk = cvt_pk_bf16(Wh[k0*1024 + m]*s, Wh[(k0+1)*1024 + m]*s);
    if (p == 0) o.x = pk; else if (p == 1) o.y = pk; else if (p == 2) o.z = pk; else o.w = pk;
  }
  whpack[t] = o;
}

// ---------------- prologue 3: repack streamed frags (kb3,kb5) contiguous per wave ---------
// wstream[dir][w][s(2)][f(8)][lane]: loop-invariant base + const offsets in main loop.
__global__ void wstream_kernel(const u32x4* __restrict__ whpack, u32x4* __restrict__ wstream){
  const int t = blockIdx.x*256 + threadIdx.x;   // 16384
  const int lane = t & 63;
  const int f    = (t >> 6) & 7;
  const int s    = (t >> 9) & 1;
  const int w    = (t >> 10) & 7;
  const int dir  = t >> 13;
  const int mf = (f >> 1)*16 + 2*w + (f & 1);
  const int kb = s ? 5 : 3;
  wstream[t] = whpack[dir*32768 + (mf*8 + kb)*64 + lane];
}

// ---------------- main: persistent LSTM ---------------------------------------------------
// grid 256 = 2 dir * 128 tiles of 16 batch rows. 512 thr = 8 waves (2/SIMD, 256 unified).
// Wave w, frag f=g*2+q -> mf=(f>>1)*16+2w+(f&1).
//   kb0,1,2,4 resident Wr, PINNED to AGPR (exactly 128 = AGPR half of the unified split)
//   kb3,kb5 via one streamed window Wg (32 regs) | kb6,7 in LDS, 4-frag JIT window
//   acc PINNED to arch-VGPR (VGPR half: acc32+Wg32+Wl16+B16+addr ~121 <= 128)
// r8/r11 spilled because the AGPR half overflowed (compiler splits the cap ~50/50);
// the zero-cost empty-asm pins make both halves fit by construction.
// No setprio (r10 regression). Barrier drains lgkm only; Wg/xz loads cross it in flight.
__global__ __launch_bounds__(512, 2) void lstm_kernel(
    const int* __restrict__ tokens, const float* __restrict__ embproj,
    const u32x4* __restrict__ whpack, const u32x4* __restrict__ wstream,
    float* __restrict__ out)
{
  const int bid = blockIdx.x;
  const int dir = bid >> 7;
  const int r0  = (bid & 127) << 4;
  const int tid = threadIdx.x;
  const int w   = tid >> 6;
  const int l   = tid & 63;
  const int l15 = l & 15;
  const int lg  = l >> 4;

  const float* ep  = embproj + dir*131072;
  const u32x4* wp  = whpack + dir*32768;
  const u32x4* wsb = wstream + ((dir*8 + w)*16)*64 + l;   // loop-invariant stream base

  __shared__ __align__(16) unsigned hbuf[2][8][64][4];   // 16 KB h double-buffer (B-frag)
  __shared__ __align__(16) u32x4 wlds[8][8][2][64];      // 128 KB: [w][f][kb-6][lane]
  __shared__ int ts[16][132];

  for (int i = tid; i < 2048; i += 512)
    ts[i >> 7][i & 127] = tokens[(r0 + (i >> 7))*128 + (i & 127)];
  for (int i = tid; i < 4096; i += 512) (&hbuf[0][0][0][0])[i] = 0u;
  #pragma unroll
  for (int f = 0; f < 8; f++)
    #pragma unroll
    for (int kbh = 0; kbh < 2; kbh++)
      wlds[w][f][kbh][l] = wp[(((f >> 1)*16 + 2*w + (f & 1))*8 + 6 + kbh)*64 + l];

  // resident: kb0,1,2 (j=0..2), kb4 (j=3) -> 32 frags = 128 regs, pinned to AGPR
  bf16x8 Wr[8][4];
  #pragma unroll
  for (int f = 0; f < 8; f++){
    #pragma unroll
    for (int j = 0; j < 3; j++)
      Wr[f][j] = *(const bf16x8*)&wp[(((f >> 1)*16 + 2*w + (f & 1))*8 + j)*64 + l];
    Wr[f][3] = *(const bf16x8*)&wp[(((f >> 1)*16 + 2*w + (f & 1))*8 + 4)*64 + l];
  }
  #pragma unroll
  for (int f = 0; f < 8; f++)
    #pragma unroll
    for (int j = 0; j < 4; j++)
      asm("" : "+a"(Wr[f][j]));          // zero-cost class pin: live range -> AGPR
  __syncthreads();

  f32x4 c4[2] = {{0.f,0.f,0.f,0.f},{0.f,0.f,0.f,0.f}};

  // prologue: xz(0) -> acc (C-init, pinned to VGPR); Wg <- kb3
  f32x4 acc[8];
  {
    const int tok0 = ts[l15][dir ? 127 : 0];
    const float* gp = ep + tok0*1024 + 32*w + lg*4;
    #pragma unroll
    for (int f = 0; f < 8; f++)
      acc[f] = *(const f32x4*)(gp + (f >> 1)*256 + (f & 1)*16);
    #pragma unroll
    for (int f = 0; f < 8; f++) asm("" : "+v"(acc[f]));
  }
  bf16x8 Wg[8];
  #pragma unroll
  for (int f = 0; f < 8; f++) Wg[f] = *(const bf16x8*)&wsb[f*64];

#define MFMA8(AW, J, BB) \
  _Pragma("unroll") \
  for (int f = 0; f < 8; f++) \
    acc[f] = __builtin_amdgcn_mfma_f32_16x16x32_bf16(AW[f][J], BB, acc[f], 0, 0, 0);
#define MFMA8W(AW, BB) \
  _Pragma("unroll") \
  for (int f = 0; f < 8; f++) \
    acc[f] = __builtin_amdgcn_mfma_f32_16x16x32_bf16(AW[f], BB, acc[f], 0, 0, 0);

// fused-rcp gates: sig(i)*tanh(g) = (G-1)*rcp((1+2^-zi)(G+1)); h = (E-1)*rcp((E+1)(1+2^-zo))
#define GATES(Q, HN) { \
  f32x4 cn; \
  _Pragma("unroll") \
  for (int r = 0; r < 4; r++){ \
    const float zi = acc[0+(Q)][r], zf = acc[2+(Q)][r], zg = acc[4+(Q)][r], zo = acc[6+(Q)][r]; \
    const float G  = __builtin_amdgcn_exp2f(zg); \
    const float sf = __builtin_amdgcn_rcpf(1.f + __builtin_amdgcn_exp2f(-zf)); \
    const float it = (G - 1.f) * __builtin_amdgcn_rcpf((1.f + __builtin_amdgcn_exp2f(-zi))*(G + 1.f)); \
    const float cc = sf*c4[Q][r] + it; \
    const float E  = __builtin_amdgcn_exp2f(LOG2E2*cc); \
    HN[r] = (E - 1.f) * __builtin_amdgcn_rcpf((E + 1.f)*(1.f + __builtin_amdgcn_exp2f(-zo))); \
    cn[r] = cc; \
  } \
  c4[Q] = cn; }

  f32x4 hn0, hn1;

  for (int t = 0; t < 128; t++){
    const int tn    = (t < 127) ? t + 1 : 127;
    const int tok_n = ts[l15][dir ? (127 - tn) : tn];
    const int rb = t & 1;

    bf16x8 B0 = *(const bf16x8*)&hbuf[rb][0][l][0];
    bf16x8 B1 = *(const bf16x8*)&hbuf[rb][1][l][0];
    bf16x8 B2 = *(const bf16x8*)&hbuf[rb][2][l][0];
    MFMA8(Wr, 0, B0);                         // kb0
    bf16x8 B3 = *(const bf16x8*)&hbuf[rb][3][l][0];
    MFMA8(Wr, 1, B1);                         // kb1
    bf16x8 B4 = *(const bf16x8*)&hbuf[rb][4][l][0];
    MFMA8(Wr, 2, B2);                         // kb2
    bf16x8 B6 = *(const bf16x8*)&hbuf[rb][6][l][0];
    MFMA8W(Wg, B3);                           // kb3 (streamed, loaded prev step)
    // refill window: kb5 (consumed ~5 groups below; L2-hot)
    #pragma unroll
    for (int f = 0; f < 8; f++) Wg[f] = *(const bf16x8*)&wsb[(8 + f)*64];
    bf16x8 B7 = *(const bf16x8*)&hbuf[rb][7][l][0];
    MFMA8(Wr, 3, B4);                         // kb4 (resident)
    bf16x8 B5 = *(const bf16x8*)&hbuf[rb][5][l][0];
    // kb6/kb7 from LDS, one 4-frag JIT window
    {
      bf16x8 Wl[4];
      #pragma unroll
      for (int j = 0; j < 4; j++) Wl[j] = *(const bf16x8*)&wlds[w][j][0][l];
      #pragma unroll
      for (int f = 0; f < 4; f++)
        acc[f] = __builtin_amdgcn_mfma_f32_16x16x32_bf16(Wl[f], B6, acc[f], 0, 0, 0);
      #pragma unroll
      for (int j = 0; j < 4; j++) Wl[j] = *(const bf16x8*)&wlds[w][4 + j][0][l];
      #pragma unroll
      for (int f = 4; f < 8; f++)
        acc[f] = __builtin_amdgcn_mfma_f32_16x16x32_bf16(Wl[f - 4], B6, acc[f], 0, 0, 0);
      #pragma unroll
      for (int j = 0; j < 4; j++) Wl[j] = *(const bf16x8*)&wlds[w][j][1][l];
      #pragma unroll
      for (int f = 0; f < 4; f++)
        acc[f] = __builtin_amdgcn_mfma_f32_16x16x32_bf16(Wl[f], B7, acc[f], 0, 0, 0);
      #pragma unroll
      for (int j = 0; j < 4; j++) Wl[j] = *(const bf16x8*)&wlds[w][4 + j][1][l];
      #pragma unroll
      for (int f = 4; f < 8; f++)
        acc[f] = __builtin_amdgcn_mfma_f32_16x16x32_bf16(Wl[f - 4], B7, acc[f], 0, 0, 0);
    }
    MFMA8W(Wg, B5);                           // kb5 (streamed)

    // gates (read acc), then overwrite acc with xz(t+1)
    GATES(0, hn0);
    GATES(1, hn1);

    u32x4 pk;
    pk.x = cvt_pk_bf16(hn0[0], hn0[1]);
    pk.y = cvt_pk_bf16(hn0[2], hn0[3]);
    pk.z = cvt_pk_bf16(hn1[0], hn1[1]);
    pk.w = cvt_pk_bf16(hn1[2], hn1[3]);
    if (t == 127){
      const int b = r0 + l15;
      const int u0 = 32*w + lg*4;
      *(f32x4*)(out + b*512 + dir*256 + u0)                    = hn0;
      *(f32x4*)(out + b*512 + dir*256 + u0 + 16)               = hn1;
      *(f32x4*)(out + 1048576 + dir*1048576 + b*256 + u0)      = hn0;
      *(f32x4*)(out + 1048576 + dir*1048576 + b*256 + u0 + 16) = hn1;
    }
    *(u32x4*)&hbuf[rb ^ 1][w][l][0] = pk;

    // next step's stream window (kb3) + xz(t+1): in flight across the barrier
    #pragma unroll
    for (int f = 0; f < 8; f++) Wg[f] = *(const bf16x8*)&wsb[f*64];
    const float* gpn = ep + tok_n*1024 + 32*w + lg*4;
    #pragma unroll
    for (int f = 0; f < 8; f++)
      acc[f] = *(const f32x4*)(gpn + (f >> 1)*256 + (f & 1)*16);
    #pragma unroll
    for (int f = 0; f < 8; f++) asm("" : "+v"(acc[f]));   // keep acc in arch-VGPR half

    asm volatile("s_waitcnt lgkmcnt(0)" ::: "memory");
    __builtin_amdgcn_s_barrier();
    __builtin_amdgcn_sched_barrier(0);
  }

  #pragma unroll
  for (int q = 0; q < 2; q++){
    const int b  = r0 + l15;
    const int u0 = 32*w + 16*q + lg*4;
    *(f32x4*)(out + 1572864 + dir*1048576 + b*256 + u0) = c4[q];
  }
#undef MFMA8
#undef MFMA8W
#undef GATES
}

extern "C" void kernel_launch(void* const* d_in, const int* in_sizes, int n_in,
                              void* d_out, int out_size, void* d_ws, size_t ws_size,
                              hipStream_t stream){
  const int*   tokens = (const int*)  d_in[0];
  const float* emb    = (const float*)d_in[1];
  const float* Wx_f   = (const float*)d_in[2];
  const float* Wh_f   = (const float*)d_in[3];
  const float* b_f    = (const float*)d_in[4];
  const float* Wx_b   = (const float*)d_in[5];
  const float* Wh_b   = (const float*)d_in[6];
  const float* b_b    = (const float*)d_in[7];
  float* out = (float*)d_out;

  // ws: embproj 1 MB | whpack 1 MB | wstream 256 KB
  float*  embproj = (float*)d_ws;
  u32x4*  whpack  = (u32x4*)(embproj + 262144);
  u32x4*  wstream = whpack + 65536;

  embproj_kernel<<<1024, 256, 0, stream>>>(emb, Wx_f, b_f, Wx_b, b_b, embproj);
  whpack_kernel<<<256, 256, 0, stream>>>(Wh_f, Wh_b, whpack);
  wstream_kernel<<<64, 256, 0, stream>>>(whpack, wstream);
  lstm_kernel<<<256, 512, 0, stream>>>(tokens, embproj, whpack, wstream, out);
}

// Round 13
// 408.715 us; speedup vs baseline: 1.9024x; 1.9024x over previous
//
#include <hip/hip_runtime.h>

typedef __attribute__((ext_vector_type(8))) short bf16x8;
typedef __attribute__((ext_vector_type(4))) float f32x4;
typedef __attribute__((ext_vector_type(2))) unsigned int u32x2;
typedef __attribute__((ext_vector_type(4))) unsigned int u32x4;

#define LOG2E  1.442695040888963f
#define LOG2E2 2.885390081777927f

__device__ __forceinline__ unsigned cvt_pk_bf16(float lo, float hi){
  unsigned r; asm("v_cvt_pk_bf16_f32 %0, %1, %2" : "=v"(r) : "v"(lo), "v"(hi)); return r;
}

// ---------------- prologue 1: embproj[dir][tok][m] = bf16((emb[tok]@Wx + b)*gate_scale) ---
__global__ void embproj_kernel(const float* __restrict__ emb,
                               const float* __restrict__ Wx_f, const float* __restrict__ b_f,
                               const float* __restrict__ Wx_b, const float* __restrict__ b_b,
                               unsigned short* __restrict__ embproj){
  const int blk = blockIdx.x;
  const int dir = blk >> 9;
  const int tok = (blk >> 2) & 127;
  const int m   = (blk & 3)*256 + threadIdx.x;
  const float* Wx = dir ? Wx_b : Wx_f;
  const float* bb = dir ? b_b  : b_f;
  __shared__ float es[128];
  if (threadIdx.x < 128) es[threadIdx.x] = emb[tok*128 + threadIdx.x];
  __syncthreads();
  float acc = bb[m];
  #pragma unroll 4
  for (int e = 0; e < 128; e++) acc = fmaf(es[e], Wx[e*1024 + m], acc);
  const float s = ((m >> 8) == 2) ? LOG2E2 : LOG2E;
  embproj[(dir*128 + tok)*1024 + m] = (unsigned short)cvt_pk_bf16(acc*s, acc*s);
}

// ---------------- prologue 2: pack Wh^T into MFMA A-frag order (bf16), pre-scaled ---------
// frag layout: [dir][mf(64)][kb(8)][lane(64)] x 16B; m = mf*16+(l&15),
// k-slot j: k = kb*32 + (l>>4)*4 + (j&3) + 16*(j>>2)   (A and B share the map)
__global__ void whpack_kernel(const float* __restrict__ Wh_f, const float* __restrict__ Wh_b,
                              u32x4* __restrict__ whpack){
  const int t = blockIdx.x*256 + threadIdx.x;
  const int lane = t & 63;
  const int kb   = (t >> 6) & 7;
  const int mf   = (t >> 9) & 63;
  const int dir  = t >> 15;
  const float* Wh = dir ? Wh_b : Wh_f;
  const int m = mf*16 + (lane & 15);
  const int kbase = kb*32 + ((lane >> 4) << 2);
  const float s = ((mf >> 4) == 2) ? LOG2E2 : LOG2E;
  u32x4 o;
  #pragma unroll
  for (int p = 0; p < 4; p++){
    const int k0 = kbase + (p & 1)*2 + (p >> 1)*16;
    unsigned pk = cvt_pk_bf16(Wh[k0*1024 + m]*s, Wh[(k0+1)*1024 + m]*s);
    if (p == 0) o.x = pk; else if (p == 1) o.y = pk; else if (p == 2) o.z = pk; else o.w = pk;
  }
  whpack[t] = o;
}

// ---------------- prologue 3: repack streamed frags (kb3,kb5) contiguous per wave ---------
__global__ void wstream_kernel(const u32x4* __restrict__ whpack, u32x4* __restrict__ wstream){
  const int t = blockIdx.x*256 + threadIdx.x;   // 16384
  const int lane = t & 63;
  const int f    = (t >> 6) & 7;
  const int s    = (t >> 9) & 1;
  const int w    = (t >> 10) & 7;
  const int dir  = t >> 13;
  const int mf = (f >> 1)*16 + 2*w + (f & 1);
  const int kb = s ? 5 : 3;
  wstream[t] = whpack[dir*32768 + (mf*8 + kb)*64 + lane];
}

// ---------------- main: persistent LSTM (r8 structure + bf16 xz + fused gates) ------------
// grid 256 = 2 dir * 128 tiles of 16 batch rows. 512 thr = 8 waves (2/SIMD, 256 unified).
// Wave w, frag f=g*2+q -> mf=(f>>1)*16+2w+(f&1).
//   kb0,1,2,4 resident Wr | kb3,kb5 via one streamed window Wg | kb6,7 LDS, 4-frag JIT
// xz carried as raw bf16 u32x2 across the barrier (no vmcnt drain before barrier);
// converted to f32 C-init at step top, overlapping B0 ds_read latency.
// No setprio (r10), no class pins (r12). Barrier drains lgkm only.
__global__ __launch_bounds__(512, 2) void lstm_kernel(
    const int* __restrict__ tokens, const unsigned short* __restrict__ embproj,
    const u32x4* __restrict__ whpack, const u32x4* __restrict__ wstream,
    float* __restrict__ out)
{
  const int bid = blockIdx.x;
  const int dir = bid >> 7;
  const int r0  = (bid & 127) << 4;
  const int tid = threadIdx.x;
  const int w   = tid >> 6;
  const int l   = tid & 63;
  const int l15 = l & 15;
  const int lg  = l >> 4;

  const unsigned short* ep = embproj + dir*131072;
  const u32x4* wp  = whpack + dir*32768;
  const u32x4* wsb = wstream + ((dir*8 + w)*16)*64 + l;   // loop-invariant stream base

  __shared__ __align__(16) unsigned hbuf[2][8][64][4];   // 16 KB h double-buffer (B-frag)
  __shared__ __align__(16) u32x4 wlds[8][8][2][64];      // 128 KB: [w][f][kb-6][lane]
  __shared__ int ts[16][132];

  for (int i = tid; i < 2048; i += 512)
    ts[i >> 7][i & 127] = tokens[(r0 + (i >> 7))*128 + (i & 127)];
  for (int i = tid; i < 4096; i += 512) (&hbuf[0][0][0][0])[i] = 0u;
  #pragma unroll
  for (int f = 0; f < 8; f++)
    #pragma unroll
    for (int kbh = 0; kbh < 2; kbh++)
      wlds[w][f][kbh][l] = wp[(((f >> 1)*16 + 2*w + (f & 1))*8 + 6 + kbh)*64 + l];

  // resident: kb0,1,2 (j=0..2), kb4 (j=3) -> 32 frags = 128 regs
  bf16x8 Wr[8][4];
  #pragma unroll
  for (int f = 0; f < 8; f++){
    #pragma unroll
    for (int j = 0; j < 3; j++)
      Wr[f][j] = *(const bf16x8*)&wp[(((f >> 1)*16 + 2*w + (f & 1))*8 + j)*64 + l];
    Wr[f][3] = *(const bf16x8*)&wp[(((f >> 1)*16 + 2*w + (f & 1))*8 + 4)*64 + l];
  }
  __syncthreads();

  f32x4 c4[2] = {{0.f,0.f,0.f,0.f},{0.f,0.f,0.f,0.f}};

  // prologue: xz(0) raw bf16 -> xzu; Wg <- kb3
  u32x2 xzu[8];
  {
    const int tok0 = ts[l15][dir ? 127 : 0];
    const unsigned short* gp = ep + tok0*1024 + 32*w + lg*4;
    #pragma unroll
    for (int f = 0; f < 8; f++)
      xzu[f] = *(const u32x2*)(gp + (f >> 1)*256 + (f & 1)*16);
  }
  bf16x8 Wg[8];
  #pragma unroll
  for (int f = 0; f < 8; f++) Wg[f] = *(const bf16x8*)&wsb[f*64];

#define MFMA8(AW, J, BB) \
  _Pragma("unroll") \
  for (int f = 0; f < 8; f++) \
    acc[f] = __builtin_amdgcn_mfma_f32_16x16x32_bf16(AW[f][J], BB, acc[f], 0, 0, 0);
#define MFMA8W(AW, BB) \
  _Pragma("unroll") \
  for (int f = 0; f < 8; f++) \
    acc[f] = __builtin_amdgcn_mfma_f32_16x16x32_bf16(AW[f], BB, acc[f], 0, 0, 0);

// fused-rcp gates: sig(i)*tanh(g) = (G-1)*rcp((1+2^-zi)(G+1)); h = (E-1)*rcp((E+1)(1+2^-zo))
#define GATES(Q, HN) { \
  f32x4 cn; \
  _Pragma("unroll") \
  for (int r = 0; r < 4; r++){ \
    const float zi = acc[0+(Q)][r], zf = acc[2+(Q)][r], zg = acc[4+(Q)][r], zo = acc[6+(Q)][r]; \
    const float G  = __builtin_amdgcn_exp2f(zg); \
    const float sf = __builtin_amdgcn_rcpf(1.f + __builtin_amdgcn_exp2f(-zf)); \
    const float it = (G - 1.f) * __builtin_amdgcn_rcpf((1.f + __builtin_amdgcn_exp2f(-zi))*(G + 1.f)); \
    const float cc = sf*c4[Q][r] + it; \
    const float E  = __builtin_amdgcn_exp2f(LOG2E2*cc); \
    HN[r] = (E - 1.f) * __builtin_amdgcn_rcpf((E + 1.f)*(1.f + __builtin_amdgcn_exp2f(-zo))); \
    cn[r] = cc; \
  } \
  c4[Q] = cn; }

  f32x4 hn0, hn1;

  for (int t = 0; t < 128; t++){
    const int tn    = (t < 127) ? t + 1 : 127;
    const int tok_n = ts[l15][dir ? (127 - tn) : tn];
    const int rb = t & 1;

    // C-init: unpack carried bf16 xz -> f32 (overlaps B0 ds_read latency)
    f32x4 acc[8];
    #pragma unroll
    for (int f = 0; f < 8; f++){
      acc[f][0] = __uint_as_float(xzu[f].x << 16);
      acc[f][1] = __uint_as_float(xzu[f].x & 0xFFFF0000u);
      acc[f][2] = __uint_as_float(xzu[f].y << 16);
      acc[f][3] = __uint_as_float(xzu[f].y & 0xFFFF0000u);
    }

    bf16x8 B0 = *(const bf16x8*)&hbuf[rb][0][l][0];
    bf16x8 B1 = *(const bf16x8*)&hbuf[rb][1][l][0];
    bf16x8 B2 = *(const bf16x8*)&hbuf[rb][2][l][0];
    MFMA8(Wr, 0, B0);                         // kb0
    bf16x8 B3 = *(const bf16x8*)&hbuf[rb][3][l][0];
    MFMA8(Wr, 1, B1);                         // kb1
    bf16x8 B4 = *(const bf16x8*)&hbuf[rb][4][l][0];
    MFMA8(Wr, 2, B2);                         // kb2
    bf16x8 B6 = *(const bf16x8*)&hbuf[rb][6][l][0];
    MFMA8W(Wg, B3);                           // kb3 (streamed, loaded prev step)
    // refill window: kb5 (consumed ~5 groups below; L2-hot)
    #pragma unroll
    for (int f = 0; f < 8; f++) Wg[f] = *(const bf16x8*)&wsb[(8 + f)*64];
    bf16x8 B7 = *(const bf16x8*)&hbuf[rb][7][l][0];
    MFMA8(Wr, 3, B4);                         // kb4 (resident)
    bf16x8 B5 = *(const bf16x8*)&hbuf[rb][5][l][0];
    // kb6/kb7 from LDS, one 4-frag JIT window
    {
      bf16x8 Wl[4];
      #pragma unroll
      for (int j = 0; j < 4; j++) Wl[j] = *(const bf16x8*)&wlds[w][j][0][l];
      #pragma unroll
      for (int f = 0; f < 4; f++)
        acc[f] = __builtin_amdgcn_mfma_f32_16x16x32_bf16(Wl[f], B6, acc[f], 0, 0, 0);
      #pragma unroll
      for (int j = 0; j < 4; j++) Wl[j] = *(const bf16x8*)&wlds[w][4 + j][0][l];
      #pragma unroll
      for (int f = 4; f < 8; f++)
        acc[f] = __builtin_amdgcn_mfma_f32_16x16x32_bf16(Wl[f - 4], B6, acc[f], 0, 0, 0);
      #pragma unroll
      for (int j = 0; j < 4; j++) Wl[j] = *(const bf16x8*)&wlds[w][j][1][l];
      #pragma unroll
      for (int f = 0; f < 4; f++)
        acc[f] = __builtin_amdgcn_mfma_f32_16x16x32_bf16(Wl[f], B7, acc[f], 0, 0, 0);
      #pragma unroll
      for (int j = 0; j < 4; j++) Wl[j] = *(const bf16x8*)&wlds[w][4 + j][1][l];
      #pragma unroll
      for (int f = 4; f < 8; f++)
        acc[f] = __builtin_amdgcn_mfma_f32_16x16x32_bf16(Wl[f - 4], B7, acc[f], 0, 0, 0);
    }
    MFMA8W(Wg, B5);                           // kb5 (streamed)

    // gates (fused-rcp), h pack
    GATES(0, hn0);
    GATES(1, hn1);

    u32x4 pk;
    pk.x = cvt_pk_bf16(hn0[0], hn0[1]);
    pk.y = cvt_pk_bf16(hn0[2], hn0[3]);
    pk.z = cvt_pk_bf16(hn1[0], hn1[1]);
    pk.w = cvt_pk_bf16(hn1[2], hn1[3]);
    if (t == 127){
      const int b = r0 + l15;
      const int u0 = 32*w + lg*4;
      *(f32x4*)(out + b*512 + dir*256 + u0)                    = hn0;
      *(f32x4*)(out + b*512 + dir*256 + u0 + 16)               = hn1;
      *(f32x4*)(out + 1048576 + dir*1048576 + b*256 + u0)      = hn0;
      *(f32x4*)(out + 1048576 + dir*1048576 + b*256 + u0 + 16) = hn1;
    }
    *(u32x4*)&hbuf[rb ^ 1][w][l][0] = pk;

    // next step's stream window (kb3) + xz(t+1) raw bf16: in flight across the barrier
    #pragma unroll
    for (int f = 0; f < 8; f++) Wg[f] = *(const bf16x8*)&wsb[f*64];
    const unsigned short* gpn = ep + tok_n*1024 + 32*w + lg*4;
    #pragma unroll
    for (int f = 0; f < 8; f++)
      xzu[f] = *(const u32x2*)(gpn + (f >> 1)*256 + (f & 1)*16);

    asm volatile("s_waitcnt lgkmcnt(0)" ::: "memory");
    __builtin_amdgcn_s_barrier();
    __builtin_amdgcn_sched_barrier(0);
  }

  #pragma unroll
  for (int q = 0; q < 2; q++){
    const int b  = r0 + l15;
    const int u0 = 32*w + 16*q + lg*4;
    *(f32x4*)(out + 1572864 + dir*1048576 + b*256 + u0) = c4[q];
  }
#undef MFMA8
#undef MFMA8W
#undef GATES
}

extern "C" void kernel_launch(void* const* d_in, const int* in_sizes, int n_in,
                              void* d_out, int out_size, void* d_ws, size_t ws_size,
                              hipStream_t stream){
  const int*   tokens = (const int*)  d_in[0];
  const float* emb    = (const float*)d_in[1];
  const float* Wx_f   = (const float*)d_in[2];
  const float* Wh_f   = (const float*)d_in[3];
  const float* b_f    = (const float*)d_in[4];
  const float* Wx_b   = (const float*)d_in[5];
  const float* Wh_b   = (const float*)d_in[6];
  const float* b_b    = (const float*)d_in[7];
  float* out = (float*)d_out;

  // ws: embproj 512 KB (bf16) | whpack 1 MB | wstream 256 KB
  unsigned short* embproj = (unsigned short*)d_ws;
  u32x4* whpack  = (u32x4*)((char*)d_ws + (1 << 19));
  u32x4* wstream = (u32x4*)((char*)d_ws + (1 << 19) + (1 << 20));

  embproj_kernel<<<1024, 256, 0, stream>>>(emb, Wx_f, b_f, Wx_b, b_b, embproj);
  whpack_kernel<<<256, 256, 0, stream>>>(Wh_f, Wh_b, whpack);
  wstream_kernel<<<64, 256, 0, stream>>>(whpack, wstream);
  lstm_kernel<<<256, 512, 0, stream>>>(tokens, embproj, whpack, wstream, out);
}